// Round 18
// baseline (111.834 us; speedup 1.0000x reference)
//
#include <hip/hip_runtime.h>
#include <hip/hip_bf16.h>

typedef __attribute__((ext_vector_type(8))) short short8;
typedef __attribute__((ext_vector_type(4))) float f32x4;
typedef __attribute__((ext_vector_type(4))) unsigned int u32x4;

#define HWPIX 147456   // 384*384
#define NC 64
#define NO 64
#define NM 4
#define EPSV 1e-5f

// f32 pair -> packed bf16x2, round-to-nearest-even (hardware instruction).
static __device__ __forceinline__ unsigned int cvt_pk(float a, float b) {
    unsigned int r;
    asm("v_cvt_pk_bf16_f32 %0, %1, %2" : "=v"(r) : "v"(a), "v"(b));
    return r;
}

// R18: zero-LDS, zero-barrier, fully independent waves (R5 structure minus
// its 4x redundancy).  Wave owns a distinct 16-px subtile per iter and holds
// ALL o-slices of W in registers (1-term bf16, R17-proven numerics).
// Frag-aligned LN (R5-proven): lane (g4,p16) loads channels {g4*8+j,
// 32+g4*8+j} of pixel p16 == its MFMA A-fragment -> no cross-lane exchange.
// Epilogue: sum_m max(z,q) - 4q (R4-proven); nt stores (R14-proven).
__global__ __launch_bounds__(256) void dnm_fused(
    const float* __restrict__ x, const float* __restrict__ Wg,
    const float* __restrict__ qp, const float* __restrict__ gamma,
    const float* __restrict__ beta, float* __restrict__ out)
{
    const int tid = threadIdx.x;
    const int wv  = tid >> 6;        // wave 0..3 (owns 128-px quarter of strip)
    const int ln  = tid & 63;
    const int p16 = ln & 15;         // pixel within subtile / W-frag B-row
    const int g4  = ln >> 4;         // k-chunk group 0..3

    const int bid = blockIdx.x;      // 1152 blocks: 288 strips of 512 px per image
    const int b       = bid / 288;
    const int pixbase = (bid % 288) * 512 + wv * 128;   // wave-private 128 px

    const float qv = qp[0];
    const float q4 = 4.0f * qv;

    // ---- W' = gamma .* W -> bf16 (RNE), ALL 4 o-slices; bias[m][os] =
    // sum_c beta_c * W[m][o][c] for o = os*16+p16.
    // Frag lane entry (os,m,ch): o = os*16+p16, k-chunk c = ch*32+g4*8+j.
    f32x4 gA[2], gB[2], bA[2], bB[2];
#pragma unroll
    for (int ch = 0; ch < 2; ++ch) {
        gA[ch] = *(const f32x4*)(gamma + ch * 32 + g4 * 8);
        gB[ch] = *(const f32x4*)(gamma + ch * 32 + g4 * 8 + 4);
        bA[ch] = *(const f32x4*)(beta  + ch * 32 + g4 * 8);
        bB[ch] = *(const f32x4*)(beta  + ch * 32 + g4 * 8 + 4);
    }
    short8 wh[NM][4][2];
    float  bias[NM][4];
#pragma unroll
    for (int m = 0; m < NM; ++m) {
#pragma unroll
        for (int os = 0; os < 4; ++os) {
            float bsum = 0.f;
#pragma unroll
            for (int ch = 0; ch < 2; ++ch) {
                const float* wp = Wg + ((m * NO + (os * 16 + p16)) * NC + ch * 32 + g4 * 8);
                f32x4 a = *(const f32x4*)(wp);
                f32x4 c = *(const f32x4*)(wp + 4);
                float f[8]  = {a[0], a[1], a[2], a[3], c[0], c[1], c[2], c[3]};
                float gg[8] = {gA[ch][0], gA[ch][1], gA[ch][2], gA[ch][3],
                               gB[ch][0], gB[ch][1], gB[ch][2], gB[ch][3]};
                float bb[8] = {bA[ch][0], bA[ch][1], bA[ch][2], bA[ch][3],
                               bB[ch][0], bB[ch][1], bB[ch][2], bB[ch][3]};
                float wq[8];
#pragma unroll
                for (int j = 0; j < 8; ++j) {
                    bsum += bb[j] * f[j];
                    wq[j] = gg[j] * f[j];
                }
                u32x4 hu;
#pragma unroll
                for (int p = 0; p < 4; ++p) hu[p] = cvt_pk(wq[2*p], wq[2*p+1]);
                wh[m][os][ch] = __builtin_bit_cast(short8, hu);
            }
            bsum += __shfl_xor(bsum, 16);
            bsum += __shfl_xor(bsum, 32);   // full sum over c for this o
            bias[m][os] = bsum;
        }
    }

    // x base: pixel column p16 of the wave's strip; channels g4*8.. (frag-aligned)
    const float* xpl = x + (size_t)b * NC * HWPIX + pixbase + p16
                         + (size_t)(g4 * 8) * HWPIX;
    // out base: o-row p16 (os offset added per-store), pixel g4*4
    float* const outw = out + (size_t)b * NO * HWPIX + (size_t)p16 * HWPIX
                            + pixbase + g4 * 4;

    // prologue: loads for it=0  (channels {g4*8+j, 32+g4*8+j} of pixel p16)
    float xv[16];
#pragma unroll
    for (int j = 0; j < 8; ++j) {
        xv[j]     = xpl[(size_t)j * HWPIX];
        xv[8 + j] = xpl[(size_t)(32 + j) * HWPIX];
    }

#pragma unroll 1
    for (int it = 0; it < 8; ++it) {
        // ---- LN on prefetched xv (one pixel per lane-column, once)
        float s1 = 0.f, s2 = 0.f;
#pragma unroll
        for (int i = 0; i < 16; ++i) { s1 += xv[i]; s2 += xv[i] * xv[i]; }
        s1 += __shfl_xor(s1, 16);  s2 += __shfl_xor(s2, 16);
        s1 += __shfl_xor(s1, 32);  s2 += __shfl_xor(s2, 32);
        const float mu  = s1 * (1.f / 64.f);
        const float var = s2 * (1.f / 64.f) - mu * mu;   // biased (torch)
        const float rs  = rsqrtf(var + EPSV);

        // xn -> bf16 A-fragments, in-lane (frag-aligned mapping, R5-proven)
        u32x4 h0, h1;
#pragma unroll
        for (int p = 0; p < 4; ++p) {
            h0[p] = cvt_pk((xv[2*p]   - mu) * rs, (xv[2*p+1] - mu) * rs);
            h1[p] = cvt_pk((xv[8+2*p] - mu) * rs, (xv[9+2*p] - mu) * rs);
        }
        short8 ah[2] = {__builtin_bit_cast(short8, h0), __builtin_bit_cast(short8, h1)};

        // ---- issue next iter's loads now (no barrier; fly under MFMA+stores)
        if (it < 7) {
            const float* xp = xpl + (it + 1) * 16;
#pragma unroll
            for (int j = 0; j < 8; ++j) {
                xv[j]     = xp[(size_t)j * HWPIX];
                xv[8 + j] = xp[(size_t)(32 + j) * HWPIX];
            }
        }

        // ---- MFMA: this wave's 16 px x ALL 64 outputs (4 o-slices)
#pragma unroll
        for (int os = 0; os < 4; ++os) {
            f32x4 acc[NM];
#pragma unroll
            for (int m = 0; m < NM; ++m) {
                f32x4 a = {bias[m][os], bias[m][os], bias[m][os], bias[m][os]};
#pragma unroll
                for (int ch = 0; ch < 2; ++ch) {
                    // 1-term: xh*Wh (R17-proven, absmax 0.15625)
                    a = __builtin_amdgcn_mfma_f32_16x16x32_bf16(ah[ch], wh[m][os][ch], a, 0, 0, 0);
                }
                acc[m] = a;
            }
            // sum_m relu(z-q) = sum_m max(z,q) - 4q; D: col(p16)=o-local,
            // row(g4*4+rr)=pixel-local (R5-proven store mapping)
            f32x4 v;
#pragma unroll
            for (int rr = 0; rr < 4; ++rr) {
                v[rr] = (fmaxf(acc[0][rr], qv) + fmaxf(acc[1][rr], qv))
                      + (fmaxf(acc[2][rr], qv) + fmaxf(acc[3][rr], qv)) - q4;
            }
            __builtin_nontemporal_store(
                v, (f32x4*)(outw + (size_t)(os * 16) * HWPIX + it * 16));
        }
    }
}

extern "C" void kernel_launch(void* const* d_in, const int* in_sizes, int n_in,
                              void* d_out, int out_size, void* d_ws, size_t ws_size,
                              hipStream_t stream) {
    const float* x     = (const float*)d_in[0];
    const float* Wg    = (const float*)d_in[1];
    const float* q     = (const float*)d_in[2];
    const float* gamma = (const float*)d_in[3];
    const float* beta  = (const float*)d_in[4];
    float* out = (float*)d_out;

    // 4 images * 288 strips of 512 px = 1152 blocks; 4 independent waves each
    dnm_fused<<<dim3(1152), dim3(256), 0, stream>>>(x, Wg, q, gamma, beta, out);
}